// Round 6
// baseline (278.767 us; speedup 1.0000x reference)
//
#include <hip/hip_runtime.h>
#include <cstdint>
#include <cmath>

#define D_MODEL 1024
#define SEQ 2048
#define BATCH 4

typedef short bf16x8 __attribute__((ext_vector_type(8)));
typedef float f32x4 __attribute__((ext_vector_type(4)));

__device__ __forceinline__ short f2bf(float f) {
  union { float f; unsigned int u; } v; v.f = f;
  unsigned int r = (v.u + 0x7FFFu + ((v.u >> 16) & 1u)) >> 16;
  return (short)r;
}

__device__ __forceinline__ float bf2f(short h) {
  union { unsigned int u; float f; } v;
  v.u = ((unsigned int)(unsigned short)h) << 16;
  return v.f;
}

__device__ __forceinline__ f32x4 mfma16(bf16x8 a, bf16x8 b, f32x4 c) {
  return __builtin_amdgcn_mfma_f32_16x16x32_bf16(a, b, c, 0, 0, 0);
}

__device__ __forceinline__ void load_lds16(const void* g, void* l) {
  __builtin_amdgcn_global_load_lds(
      (const __attribute__((address_space(1))) unsigned int*)g,
      (__attribute__((address_space(3))) unsigned int*)l, 16, 0, 0);
}

// ---------------- prep: x fp32 -> bf16 ----------------
__global__ __launch_bounds__(256) void convert_x(const float* __restrict__ x,
                                                 short* __restrict__ xb) {
  int i = blockIdx.x * 256 + threadIdx.x;
  float4 f = ((const float4*)x)[i];
  short4 h;
  h.x = f2bf(f.x); h.y = f2bf(f.y); h.z = f2bf(f.z); h.w = f2bf(f.w);
  ((short4*)xb)[i] = h;
}

// ---------------- prep: W [k][n] fp32 -> Wt [n][k] bf16 ----------------
__global__ __launch_bounds__(256) void transpose_w(const float* __restrict__ Wq,
                                                   const float* __restrict__ Wk,
                                                   const float* __restrict__ Wv,
                                                   short* __restrict__ wt) {
  const int mat = blockIdx.z;
  const float* __restrict__ W = (mat == 0) ? Wq : (mat == 1) ? Wk : Wv;
  short* __restrict__ o = wt + (size_t)mat * (D_MODEL * D_MODEL);
  __shared__ float tile[32][33];
  const int k0 = blockIdx.x * 32, n0 = blockIdx.y * 32;
  const int lx = threadIdx.x & 31, ly = threadIdx.x >> 5;
#pragma unroll
  for (int i = 0; i < 4; ++i) {
    int r = ly + i * 8;
    tile[r][lx] = W[(size_t)(k0 + r) * D_MODEL + n0 + lx];
  }
  __syncthreads();
#pragma unroll
  for (int i = 0; i < 4; ++i) {
    int r = ly + i * 8;
    o[(size_t)(n0 + r) * D_MODEL + k0 + lx] = f2bf(tile[lx][r]);
  }
}

// Shared GEMM core pattern: 128x128 tile, 256 thr (4 waves, 2x2 of 64x64),
// BK=32, 3-stage LDS pipeline + register fragment prefetch.
// LDS row layout: 4 chunks of 8 bf16; chunk at pos p holds global chunk
// p ^ ((row>>1)&3) -> conflict-free reads with key (l16>>1)&3.

// ---------------- QKV GEMM ----------------
// C[m][n] = sum_k xb[m][k] * Wt[n][k] + bias[n]; grid (64, 8, 3)
__global__ __launch_bounds__(256) void qkv_gemm(
    const short* __restrict__ xb, const short* __restrict__ wt,
    const float* __restrict__ bq, const float* __restrict__ bk,
    const float* __restrict__ bv, short* __restrict__ qo,
    short* __restrict__ ko, short* __restrict__ vo) {
  const int m0 = blockIdx.x * 128;
  const int n0 = blockIdx.y * 128;
  const int mat = blockIdx.z;
  const short* __restrict__ w = wt + (size_t)mat * (D_MODEL * D_MODEL);
  const float* __restrict__ bias = (mat == 0) ? bq : (mat == 1) ? bk : bv;

  __shared__ short a_lds[3][128 * 32];
  __shared__ short b_lds[3][128 * 32];

  const int tid = threadIdx.x;
  const int wid = tid >> 6;
  const int lane = tid & 63;
  const int quad = lane >> 4;
  const int l16 = lane & 15;
  const int mw = (wid >> 1) * 64;
  const int nw = (wid & 1) * 64;
  const int key = (l16 >> 1) & 3;

  f32x4 acc[4][4] = {};

  auto stage = [&](int k0, int buf) {
#pragma unroll
    for (int h = 0; h < 2; ++h) {
      const int c = tid + h * 256;
      const int gc = ((c & 3) ^ ((c >> 3) & 3)) << 3;
      load_lds16(xb + (size_t)(m0 + (c >> 2)) * D_MODEL + k0 + gc,
                 (char*)&a_lds[buf][c * 8]);
      load_lds16(w + (size_t)(n0 + (c >> 2)) * D_MODEL + k0 + gc,
                 (char*)&b_lds[buf][c * 8]);
    }
  };
  auto read_frags = [&](int buf, bf16x8* af, bf16x8* bfr) {
    const short* al = a_lds[buf];
    const short* bl = b_lds[buf];
#pragma unroll
    for (int i = 0; i < 4; ++i)
      af[i] = *(const bf16x8*)(al + (mw + i * 16 + l16) * 32 + ((quad ^ key) << 3));
#pragma unroll
    for (int j = 0; j < 4; ++j)
      bfr[j] = *(const bf16x8*)(bl + (nw + j * 16 + l16) * 32 + ((quad ^ key) << 3));
  };
  auto domfma = [&](bf16x8* af, bf16x8* bfr) {
#pragma unroll
    for (int i = 0; i < 4; ++i)
#pragma unroll
      for (int j = 0; j < 4; ++j)
        acc[i][j] = mfma16(af[i], bfr[j], acc[i][j]);
  };

  const int NIT = D_MODEL / 32;  // 32
  stage(0, 0);
  stage(32, 1);
  __syncthreads();
  bf16x8 af0[4], bf0[4], af1[4], bf1[4];
  read_frags(0, af0, bf0);
  int b0 = 0, b1 = 1, b2 = 2;
  for (int k = 0; k < NIT; k += 2) {
    const int kk = k * 32;
    if (k + 2 < NIT) stage(kk + 64, b2);
    read_frags(b1, af1, bf1);
    domfma(af0, bf0);
    __syncthreads();
    if (k + 3 < NIT) stage(kk + 96, b0);
    if (k + 2 < NIT) read_frags(b2, af0, bf0);
    domfma(af1, bf1);
    __syncthreads();
    const int t0 = b0; b0 = b2; b2 = b1; b1 = t0;
  }
#pragma unroll
  for (int i = 0; i < 4; ++i) {
#pragma unroll
    for (int j = 0; j < 4; ++j) {
#pragma unroll
      for (int r = 0; r < 4; ++r) {
        const int mrow = m0 + mw + i * 16 + quad * 4 + r;
        const int ncol = n0 + nw + j * 16 + l16;
        const float val = acc[i][j][r] + bias[ncol];
        const short h = f2bf(val);
        if (mat == 2) {
          const int bb = mrow >> 11;
          const int t = mrow & 2047;
          vo[((size_t)bb * D_MODEL + ncol) * SEQ + t] = h;
        } else if (mat == 0) {
          qo[(size_t)mrow * D_MODEL + ncol] = h;
        } else {
          ko[(size_t)mrow * D_MODEL + ncol] = h;
        }
      }
    }
  }
}

// ---------------- S = scale * Q K^T, compact triangular grid (136, BATCH) -------
__global__ __launch_bounds__(256) void sgemm(const short* __restrict__ qb,
                                             const short* __restrict__ kb,
                                             short* __restrict__ S) {
  const int t = blockIdx.x;
  int r = (int)((sqrtf(8.0f * t + 1.0f) - 1.0f) * 0.5f);
  while ((r + 1) * (r + 2) / 2 <= t) ++r;
  while (r * (r + 1) / 2 > t) --r;
  const int m0 = r * 128;
  const int n0 = (t - r * (r + 1) / 2) * 128;
  const int b = blockIdx.y;
  const short* __restrict__ qp = qb + (size_t)b * SEQ * D_MODEL;
  const short* __restrict__ kp = kb + (size_t)b * SEQ * D_MODEL;

  __shared__ short a_lds[3][128 * 32];
  __shared__ short b_lds[3][128 * 32];

  const int tid = threadIdx.x;
  const int wid = tid >> 6;
  const int lane = tid & 63;
  const int quad = lane >> 4;
  const int l16 = lane & 15;
  const int mw = (wid >> 1) * 64;
  const int nw = (wid & 1) * 64;
  const int key = (l16 >> 1) & 3;

  f32x4 acc[4][4] = {};

  auto stage = [&](int k0, int buf) {
#pragma unroll
    for (int h = 0; h < 2; ++h) {
      const int c = tid + h * 256;
      const int gc = ((c & 3) ^ ((c >> 3) & 3)) << 3;
      load_lds16(qp + (size_t)(m0 + (c >> 2)) * D_MODEL + k0 + gc,
                 (char*)&a_lds[buf][c * 8]);
      load_lds16(kp + (size_t)(n0 + (c >> 2)) * D_MODEL + k0 + gc,
                 (char*)&b_lds[buf][c * 8]);
    }
  };
  auto read_frags = [&](int buf, bf16x8* af, bf16x8* bfr) {
    const short* al = a_lds[buf];
    const short* bl = b_lds[buf];
#pragma unroll
    for (int i = 0; i < 4; ++i)
      af[i] = *(const bf16x8*)(al + (mw + i * 16 + l16) * 32 + ((quad ^ key) << 3));
#pragma unroll
    for (int j = 0; j < 4; ++j)
      bfr[j] = *(const bf16x8*)(bl + (nw + j * 16 + l16) * 32 + ((quad ^ key) << 3));
  };
  auto domfma = [&](bf16x8* af, bf16x8* bfr) {
#pragma unroll
    for (int i = 0; i < 4; ++i)
#pragma unroll
      for (int j = 0; j < 4; ++j)
        acc[i][j] = mfma16(af[i], bfr[j], acc[i][j]);
  };

  const int NIT = D_MODEL / 32;
  stage(0, 0);
  stage(32, 1);
  __syncthreads();
  bf16x8 af0[4], bf0[4], af1[4], bf1[4];
  read_frags(0, af0, bf0);
  int b0 = 0, b1 = 1, b2 = 2;
  for (int k = 0; k < NIT; k += 2) {
    const int kk = k * 32;
    if (k + 2 < NIT) stage(kk + 64, b2);
    read_frags(b1, af1, bf1);
    domfma(af0, bf0);
    __syncthreads();
    if (k + 3 < NIT) stage(kk + 96, b0);
    if (k + 2 < NIT) read_frags(b2, af0, bf0);
    domfma(af1, bf1);
    __syncthreads();
    const int t0 = b0; b0 = b2; b2 = b1; b1 = t0;
  }
#pragma unroll
  for (int i = 0; i < 4; ++i) {
#pragma unroll
    for (int j = 0; j < 4; ++j) {
#pragma unroll
      for (int rr = 0; rr < 4; ++rr) {
        const int mrow = m0 + mw + i * 16 + quad * 4 + rr;
        const int ncol = n0 + nw + j * 16 + l16;
        S[((size_t)b * SEQ + mrow) * SEQ + ncol] = f2bf(acc[i][j][rr] * 0.03125f);
      }
    }
  }
}

// ---------------- row softmax: S bf16 -> P bf16 (normalized, zero-padded) --------
__global__ __launch_bounds__(256) void softmax_rows(const short* __restrict__ S,
                                                    short* __restrict__ P) {
  const int row = blockIdx.x;          // 0..8191
  const int t = row & (SEQ - 1);
  const int tid = threadIdx.x;
  const short* __restrict__ srow = S + (size_t)row * SEQ;
  short* __restrict__ prow = P + (size_t)row * SEQ;

  __shared__ float red[4];

  float v[8];
#pragma unroll
  for (int i = 0; i < 8; ++i) {
    const int c = tid + i * 256;
    v[i] = (c <= t) ? bf2f(srow[c]) : -1e30f;
  }
  float m = v[0];
#pragma unroll
  for (int i = 1; i < 8; ++i) m = fmaxf(m, v[i]);
#pragma unroll
  for (int o = 32; o; o >>= 1) m = fmaxf(m, __shfl_xor(m, o));
  if ((tid & 63) == 0) red[tid >> 6] = m;
  __syncthreads();
  m = fmaxf(fmaxf(red[0], red[1]), fmaxf(red[2], red[3]));

  float e[8];
  float s = 0.f;
#pragma unroll
  for (int i = 0; i < 8; ++i) {
    e[i] = __expf(v[i] - m);
    s += e[i];
  }
#pragma unroll
  for (int o = 32; o; o >>= 1) s += __shfl_xor(s, o);
  __syncthreads();
  if ((tid & 63) == 0) red[tid >> 6] = s;
  __syncthreads();
  s = red[0] + red[1] + red[2] + red[3];
  const float rinv = 1.0f / s;
  const int nwr = (t >> 8) + 1;
#pragma unroll
  for (int i = 0; i < 8; ++i)
    if (i < nwr) prow[tid + i * 256] = f2bf(e[i] * rinv);
}

// ---------------- O = P V (B = V^T layout), causal K ----------------------------
// grid (8,4,16): x=d tile, y=batch, z: m0=(15-z)*128 (LPT: longest-K first).
__global__ __launch_bounds__(256) void pvgemm(const short* __restrict__ P,
                                              const short* __restrict__ vtb,
                                              float* __restrict__ out) {
  const int n0 = blockIdx.x * 128;
  const int b = blockIdx.y;
  const int m0 = (15 - blockIdx.z) * 128;
  const short* __restrict__ pp = P + (size_t)b * SEQ * SEQ;
  const short* __restrict__ vp = vtb + (size_t)b * D_MODEL * SEQ;

  __shared__ short a_lds[3][128 * 32];
  __shared__ short b_lds[3][128 * 32];

  const int tid = threadIdx.x;
  const int wid = tid >> 6;
  const int lane = tid & 63;
  const int quad = lane >> 4;
  const int l16 = lane & 15;
  const int mw = (wid >> 1) * 64;
  const int nw = (wid & 1) * 64;
  const int key = (l16 >> 1) & 3;

  f32x4 acc[4][4] = {};

  auto stage = [&](int k0, int buf) {
#pragma unroll
    for (int h = 0; h < 2; ++h) {
      const int c = tid + h * 256;
      const int gc = ((c & 3) ^ ((c >> 3) & 3)) << 3;
      load_lds16(pp + (size_t)(m0 + (c >> 2)) * SEQ + k0 + gc,
                 (char*)&a_lds[buf][c * 8]);
      load_lds16(vp + (size_t)(n0 + (c >> 2)) * SEQ + k0 + gc,
                 (char*)&b_lds[buf][c * 8]);
    }
  };
  auto read_frags = [&](int buf, bf16x8* af, bf16x8* bfr) {
    const short* al = a_lds[buf];
    const short* bl = b_lds[buf];
#pragma unroll
    for (int i = 0; i < 4; ++i)
      af[i] = *(const bf16x8*)(al + (mw + i * 16 + l16) * 32 + ((quad ^ key) << 3));
#pragma unroll
    for (int j = 0; j < 4; ++j)
      bfr[j] = *(const bf16x8*)(bl + (nw + j * 16 + l16) * 32 + ((quad ^ key) << 3));
  };
  auto domfma = [&](bf16x8* af, bf16x8* bfr) {
#pragma unroll
    for (int i = 0; i < 4; ++i)
#pragma unroll
      for (int j = 0; j < 4; ++j)
        acc[i][j] = mfma16(af[i], bfr[j], acc[i][j]);
  };

  const int NIT = (m0 + 128) / 32;  // 4..64, always even
  stage(0, 0);
  stage(32, 1);
  __syncthreads();
  bf16x8 af0[4], bf0[4], af1[4], bf1[4];
  read_frags(0, af0, bf0);
  int b0 = 0, b1 = 1, b2 = 2;
  for (int k = 0; k < NIT; k += 2) {
    const int kk = k * 32;
    if (k + 2 < NIT) stage(kk + 64, b2);
    read_frags(b1, af1, bf1);
    domfma(af0, bf0);
    __syncthreads();
    if (k + 3 < NIT) stage(kk + 96, b0);
    if (k + 2 < NIT) read_frags(b2, af0, bf0);
    domfma(af1, bf1);
    __syncthreads();
    const int t0 = b0; b0 = b2; b2 = b1; b1 = t0;
  }
#pragma unroll
  for (int i = 0; i < 4; ++i) {
#pragma unroll
    for (int j = 0; j < 4; ++j) {
#pragma unroll
      for (int r = 0; r < 4; ++r) {
        const int mrow = m0 + mw + i * 16 + quad * 4 + r;
        const int ncol = n0 + nw + j * 16 + l16;
        out[((size_t)b * SEQ + mrow) * D_MODEL + ncol] = acc[i][j][r];
      }
    }
  }
}

extern "C" void kernel_launch(void* const* d_in, const int* in_sizes, int n_in,
                              void* d_out, int out_size, void* d_ws, size_t ws_size,
                              hipStream_t stream) {
  (void)in_sizes; (void)n_in; (void)out_size; (void)ws_size;
  const float* x  = (const float*)d_in[0];
  const float* Wq = (const float*)d_in[1];
  const float* bq = (const float*)d_in[2];
  const float* Wk = (const float*)d_in[3];
  const float* bk = (const float*)d_in[4];
  const float* Wv = (const float*)d_in[5];
  const float* bv = (const float*)d_in[6];
  float* out = (float*)d_out;

  char* ws = (char*)d_ws;
  short* xb = (short*)(ws);                 // 16 MB   [dead after qkv_gemm]
  short* wt = (short*)(ws + 16777216);      // 6 MB    [dead after qkv_gemm]
  short* qo = (short*)(ws + 23068672);      // 16 MB   [dead after sgemm]
  short* ko = (short*)(ws + 39845888);      // 16 MB   [dead after sgemm]
  short* vo = (short*)(ws + 56623104);      // 16 MB   transposed [b][d][s]
  short* S  = (short*)(ws + 73400320);      // 32 MB bf16 [b][t][s]
  short* P  = (short*)(ws);                 // 32 MB, aliases xb/wt/qo (dead by then)

  convert_x<<<dim3(8192), dim3(256), 0, stream>>>(x, xb);
  transpose_w<<<dim3(32, 32, 3), dim3(256), 0, stream>>>(Wq, Wk, Wv, wt);
  qkv_gemm<<<dim3(64, 8, 3), dim3(256), 0, stream>>>(xb, wt, bq, bk, bv, qo, ko, vo);
  sgemm<<<dim3(136, BATCH), dim3(256), 0, stream>>>(qo, ko, S);
  softmax_rows<<<dim3(BATCH * SEQ), dim3(256), 0, stream>>>(S, P);
  pvgemm<<<dim3(8, BATCH, 16), dim3(256), 0, stream>>>(P, vo, out);
}

// Round 7
// 267.997 us; speedup vs baseline: 1.0402x; 1.0402x over previous
//
#include <hip/hip_runtime.h>
#include <cstdint>
#include <cmath>

#define D_MODEL 1024
#define SEQ 2048
#define BATCH 4

typedef short bf16x8 __attribute__((ext_vector_type(8)));
typedef float f32x4 __attribute__((ext_vector_type(4)));

__device__ __forceinline__ short f2bf(float f) {
  union { float f; unsigned int u; } v; v.f = f;
  unsigned int r = (v.u + 0x7FFFu + ((v.u >> 16) & 1u)) >> 16;
  return (short)r;
}

__device__ __forceinline__ float bf2f(short h) {
  union { unsigned int u; float f; } v;
  v.u = ((unsigned int)(unsigned short)h) << 16;
  return v.f;
}

__device__ __forceinline__ f32x4 mfma16(bf16x8 a, bf16x8 b, f32x4 c) {
  return __builtin_amdgcn_mfma_f32_16x16x32_bf16(a, b, c, 0, 0, 0);
}

__device__ __forceinline__ void load_lds16(const void* g, void* l) {
  __builtin_amdgcn_global_load_lds(
      (const __attribute__((address_space(1))) unsigned int*)g,
      (__attribute__((address_space(3))) unsigned int*)l, 16, 0, 0);
}

// ------- prep: fused convert_x (blocks 0..8191) + transpose_w (8192..11263) -----
__global__ __launch_bounds__(256) void prep(const float* __restrict__ x,
                                            const float* __restrict__ Wq,
                                            const float* __restrict__ Wk,
                                            const float* __restrict__ Wv,
                                            short* __restrict__ xb,
                                            short* __restrict__ wt) {
  const int bx = blockIdx.x;
  if (bx < 8192) {
    const int i = bx * 256 + threadIdx.x;
    float4 f = ((const float4*)x)[i];
    short4 h;
    h.x = f2bf(f.x); h.y = f2bf(f.y); h.z = f2bf(f.z); h.w = f2bf(f.w);
    ((short4*)xb)[i] = h;
    return;
  }
  const int b2 = bx - 8192;          // 0..3071
  const int mat = b2 >> 10;          // 0..2
  const int rem = b2 & 1023;
  const int k0 = (rem & 31) * 32;
  const int n0 = (rem >> 5) * 32;
  const float* __restrict__ W = (mat == 0) ? Wq : (mat == 1) ? Wk : Wv;
  short* __restrict__ o = wt + (size_t)mat * (D_MODEL * D_MODEL);
  __shared__ float tile[32][33];
  const int lx = threadIdx.x & 31, ly = threadIdx.x >> 5;
#pragma unroll
  for (int i = 0; i < 4; ++i) {
    int r = ly + i * 8;
    tile[r][lx] = W[(size_t)(k0 + r) * D_MODEL + n0 + lx];
  }
  __syncthreads();
#pragma unroll
  for (int i = 0; i < 4; ++i) {
    int r = ly + i * 8;
    o[(size_t)(n0 + r) * D_MODEL + k0 + lx] = f2bf(tile[lx][r]);
  }
}

// ------- QKV GEMM: 256x128 tile, 512 thr, BK=32, dbuf (48 KB) — round-5 proven --
// C[m][n] = sum_k xb[m][k] * Wt[n][k] + bias[n]
__global__ __launch_bounds__(512, 4) void qkv_gemm(
    const short* __restrict__ xb, const short* __restrict__ wt,
    const float* __restrict__ bq, const float* __restrict__ bk,
    const float* __restrict__ bv, short* __restrict__ qo,
    short* __restrict__ ko, short* __restrict__ vo) {
  const int m0 = blockIdx.x * 256;
  const int n0 = blockIdx.y * 128;
  const int mat = blockIdx.z;
  const short* __restrict__ w = wt + (size_t)mat * (D_MODEL * D_MODEL);
  const float* __restrict__ bias = (mat == 0) ? bq : (mat == 1) ? bk : bv;

  __shared__ short a_lds[2][256 * 32];  // 2 x 16 KB
  __shared__ short b_lds[2][128 * 32];  // 2 x 8 KB

  const int tid = threadIdx.x;
  const int wid = tid >> 6;        // 0..7
  const int lane = tid & 63;
  const int quad = lane >> 4;
  const int l16 = lane & 15;
  const int wm = (wid >> 1) * 64;
  const int wn = (wid & 1) * 64;
  const int key = (l16 >> 1) & 3;

  f32x4 acc[4][4] = {};

  auto stage = [&](int k0, int buf) {
#pragma unroll
    for (int h = 0; h < 2; ++h) {
      const int c = tid + h * 512;
      load_lds16(xb + (size_t)(m0 + (c >> 2)) * D_MODEL + k0 +
                     (((c & 3) ^ ((c >> 3) & 3)) << 3),
                 (char*)&a_lds[buf][c * 8]);
    }
    load_lds16(w + (size_t)(n0 + (tid >> 2)) * D_MODEL + k0 +
                   (((tid & 3) ^ ((tid >> 3) & 3)) << 3),
               (char*)&b_lds[buf][tid * 8]);
  };

  stage(0, 0);
  for (int k0 = 0; k0 < D_MODEL; k0 += 32) {
    const int buf = (k0 >> 5) & 1;
    __syncthreads();
    if (k0 + 32 < D_MODEL) stage(k0 + 32, buf ^ 1);
    const short* al = a_lds[buf];
    const short* bl = b_lds[buf];
    bf16x8 af[4], bfr[4];
#pragma unroll
    for (int i = 0; i < 4; ++i)
      af[i] = *(const bf16x8*)(al + (wm + i * 16 + l16) * 32 +
                               ((quad ^ key) << 3));
#pragma unroll
    for (int j = 0; j < 4; ++j)
      bfr[j] = *(const bf16x8*)(bl + (wn + j * 16 + l16) * 32 +
                                ((quad ^ key) << 3));
#pragma unroll
    for (int i = 0; i < 4; ++i)
#pragma unroll
      for (int j = 0; j < 4; ++j)
        acc[i][j] = mfma16(af[i], bfr[j], acc[i][j]);
  }
#pragma unroll
  for (int i = 0; i < 4; ++i) {
#pragma unroll
    for (int j = 0; j < 4; ++j) {
#pragma unroll
      for (int r = 0; r < 4; ++r) {
        const int mrow = m0 + wm + i * 16 + quad * 4 + r;
        const int ncol = n0 + wn + j * 16 + l16;
        const float val = acc[i][j][r] + bias[ncol];
        const short h = f2bf(val);
        if (mat == 2) {
          const int bb = mrow >> 11;
          const int t = mrow & 2047;
          vo[((size_t)bb * D_MODEL + ncol) * SEQ + t] = h;
        } else if (mat == 0) {
          qo[(size_t)mrow * D_MODEL + ncol] = h;
        } else {
          ko[(size_t)mrow * D_MODEL + ncol] = h;
        }
      }
    }
  }
}

// ------- S = scale * Q K^T: 128x128 tile, BK=32, dbuf (32 KB), triangular grid --
__global__ __launch_bounds__(256) void sgemm(const short* __restrict__ qb,
                                             const short* __restrict__ kb,
                                             short* __restrict__ S) {
  const int t = blockIdx.x;
  int r = (int)((sqrtf(8.0f * t + 1.0f) - 1.0f) * 0.5f);
  while ((r + 1) * (r + 2) / 2 <= t) ++r;
  while (r * (r + 1) / 2 > t) --r;
  const int m0 = r * 128;
  const int n0 = (t - r * (r + 1) / 2) * 128;
  const int b = blockIdx.y;
  const short* __restrict__ qp = qb + (size_t)b * SEQ * D_MODEL;
  const short* __restrict__ kp = kb + (size_t)b * SEQ * D_MODEL;

  __shared__ short a_lds[2][128 * 32];  // 2 x 8 KB
  __shared__ short b_lds[2][128 * 32];  // 2 x 8 KB

  const int tid = threadIdx.x;
  const int wid = tid >> 6;
  const int lane = tid & 63;
  const int quad = lane >> 4;
  const int l16 = lane & 15;
  const int mw = (wid >> 1) * 64;
  const int nw = (wid & 1) * 64;
  const int key = (l16 >> 1) & 3;

  f32x4 acc[4][4] = {};

  auto stage = [&](int k0, int buf) {
#pragma unroll
    for (int h = 0; h < 2; ++h) {
      const int c = tid + h * 256;
      const int gc = ((c & 3) ^ ((c >> 3) & 3)) << 3;
      load_lds16(qp + (size_t)(m0 + (c >> 2)) * D_MODEL + k0 + gc,
                 (char*)&a_lds[buf][c * 8]);
      load_lds16(kp + (size_t)(n0 + (c >> 2)) * D_MODEL + k0 + gc,
                 (char*)&b_lds[buf][c * 8]);
    }
  };

  stage(0, 0);
  for (int k0 = 0; k0 < D_MODEL; k0 += 32) {
    const int buf = (k0 >> 5) & 1;
    __syncthreads();
    if (k0 + 32 < D_MODEL) stage(k0 + 32, buf ^ 1);
    const short* al = a_lds[buf];
    const short* bl = b_lds[buf];
    bf16x8 af[4], bfr[4];
#pragma unroll
    for (int i = 0; i < 4; ++i)
      af[i] = *(const bf16x8*)(al + (mw + i * 16 + l16) * 32 +
                               ((quad ^ key) << 3));
#pragma unroll
    for (int j = 0; j < 4; ++j)
      bfr[j] = *(const bf16x8*)(bl + (nw + j * 16 + l16) * 32 +
                                ((quad ^ key) << 3));
#pragma unroll
    for (int i = 0; i < 4; ++i)
#pragma unroll
      for (int j = 0; j < 4; ++j)
        acc[i][j] = mfma16(af[i], bfr[j], acc[i][j]);
  }
#pragma unroll
  for (int i = 0; i < 4; ++i) {
#pragma unroll
    for (int j = 0; j < 4; ++j) {
#pragma unroll
      for (int rr = 0; rr < 4; ++rr) {
        const int mrow = m0 + mw + i * 16 + quad * 4 + rr;
        const int ncol = n0 + nw + j * 16 + l16;
        S[((size_t)b * SEQ + mrow) * SEQ + ncol] = f2bf(acc[i][j][rr] * 0.03125f);
      }
    }
  }
}

// ------- row softmax: S bf16 -> P bf16; loads & stores only causal extent -------
__global__ __launch_bounds__(256) void softmax_rows(const short* __restrict__ S,
                                                    short* __restrict__ P) {
  const int row = blockIdx.x;          // 0..8191
  const int t = row & (SEQ - 1);
  const int tid = threadIdx.x;
  const short* __restrict__ srow = S + (size_t)row * SEQ;
  short* __restrict__ prow = P + (size_t)row * SEQ;

  __shared__ float red[4];

  float v[8];
#pragma unroll
  for (int i = 0; i < 8; ++i) {
    const int c = tid + i * 256;
    v[i] = -1e30f;
    if (c <= t) v[i] = bf2f(srow[c]);
  }
  float m = v[0];
#pragma unroll
  for (int i = 1; i < 8; ++i) m = fmaxf(m, v[i]);
#pragma unroll
  for (int o = 32; o; o >>= 1) m = fmaxf(m, __shfl_xor(m, o));
  if ((tid & 63) == 0) red[tid >> 6] = m;
  __syncthreads();
  m = fmaxf(fmaxf(red[0], red[1]), fmaxf(red[2], red[3]));

  float e[8];
  float s = 0.f;
#pragma unroll
  for (int i = 0; i < 8; ++i) {
    e[i] = __expf(v[i] - m);
    s += e[i];
  }
#pragma unroll
  for (int o = 32; o; o >>= 1) s += __shfl_xor(s, o);
  __syncthreads();
  if ((tid & 63) == 0) red[tid >> 6] = s;
  __syncthreads();
  s = red[0] + red[1] + red[2] + red[3];
  const float rinv = 1.0f / s;
  const int nwr = (t >> 8) + 1;   // 256-chunks covering pvgemm read extent
#pragma unroll
  for (int i = 0; i < 8; ++i)
    if (i < nwr) prow[tid + i * 256] = f2bf(e[i] * rinv);
}

// ------- O = P V (B=V^T layout): 128x128, BK=32, dbuf (32 KB), causal K, LPT ----
// grid (8,4,16): x=d tile, y=batch, z: m0=(15-z)*128 (longest-K first).
__global__ __launch_bounds__(256) void pvgemm(const short* __restrict__ P,
                                              const short* __restrict__ vtb,
                                              float* __restrict__ out) {
  const int n0 = blockIdx.x * 128;
  const int b = blockIdx.y;
  const int m0 = (15 - blockIdx.z) * 128;
  const short* __restrict__ pp = P + (size_t)b * SEQ * SEQ;
  const short* __restrict__ vp = vtb + (size_t)b * D_MODEL * SEQ;
  const int kmax = m0 + 128;

  __shared__ short a_lds[2][128 * 32];
  __shared__ short b_lds[2][128 * 32];

  const int tid = threadIdx.x;
  const int wid = tid >> 6;
  const int lane = tid & 63;
  const int quad = lane >> 4;
  const int l16 = lane & 15;
  const int mw = (wid >> 1) * 64;
  const int nw = (wid & 1) * 64;
  const int key = (l16 >> 1) & 3;

  f32x4 acc[4][4] = {};

  auto stage = [&](int k0, int buf) {
#pragma unroll
    for (int h = 0; h < 2; ++h) {
      const int c = tid + h * 256;
      const int gc = ((c & 3) ^ ((c >> 3) & 3)) << 3;
      load_lds16(pp + (size_t)(m0 + (c >> 2)) * SEQ + k0 + gc,
                 (char*)&a_lds[buf][c * 8]);
      load_lds16(vp + (size_t)(n0 + (c >> 2)) * SEQ + k0 + gc,
                 (char*)&b_lds[buf][c * 8]);
    }
  };

  stage(0, 0);
  for (int k0 = 0; k0 < kmax; k0 += 32) {
    const int buf = (k0 >> 5) & 1;
    __syncthreads();
    if (k0 + 32 < kmax) stage(k0 + 32, buf ^ 1);
    const short* al = a_lds[buf];
    const short* bl = b_lds[buf];
    bf16x8 af[4], bfr[4];
#pragma unroll
    for (int i = 0; i < 4; ++i)
      af[i] = *(const bf16x8*)(al + (mw + i * 16 + l16) * 32 +
                               ((quad ^ key) << 3));
#pragma unroll
    for (int j = 0; j < 4; ++j)
      bfr[j] = *(const bf16x8*)(bl + (nw + j * 16 + l16) * 32 +
                                ((quad ^ key) << 3));
#pragma unroll
    for (int i = 0; i < 4; ++i)
#pragma unroll
      for (int j = 0; j < 4; ++j)
        acc[i][j] = mfma16(af[i], bfr[j], acc[i][j]);
  }
#pragma unroll
  for (int i = 0; i < 4; ++i) {
#pragma unroll
    for (int j = 0; j < 4; ++j) {
#pragma unroll
      for (int r = 0; r < 4; ++r) {
        const int mrow = m0 + mw + i * 16 + quad * 4 + r;
        const int ncol = n0 + nw + j * 16 + l16;
        out[((size_t)b * SEQ + mrow) * D_MODEL + ncol] = acc[i][j][r];
      }
    }
  }
}

extern "C" void kernel_launch(void* const* d_in, const int* in_sizes, int n_in,
                              void* d_out, int out_size, void* d_ws, size_t ws_size,
                              hipStream_t stream) {
  (void)in_sizes; (void)n_in; (void)out_size; (void)ws_size;
  const float* x  = (const float*)d_in[0];
  const float* Wq = (const float*)d_in[1];
  const float* bq = (const float*)d_in[2];
  const float* Wk = (const float*)d_in[3];
  const float* bk = (const float*)d_in[4];
  const float* Wv = (const float*)d_in[5];
  const float* bv = (const float*)d_in[6];
  float* out = (float*)d_out;

  char* ws = (char*)d_ws;
  short* xb = (short*)(ws);                 // 16 MB   [dead after qkv_gemm]
  short* wt = (short*)(ws + 16777216);      // 6 MB    [dead after qkv_gemm]
  short* qo = (short*)(ws + 23068672);      // 16 MB   [dead after sgemm]
  short* ko = (short*)(ws + 39845888);      // 16 MB   [dead after sgemm]
  short* vo = (short*)(ws + 56623104);      // 16 MB   transposed [b][d][s]
  short* S  = (short*)(ws + 73400320);      // 32 MB bf16 [b][t][s]
  short* P  = (short*)(ws);                 // 32 MB, aliases xb/wt/qo (dead by then)

  prep<<<dim3(8192 + 3072), dim3(256), 0, stream>>>(x, Wq, Wk, Wv, xb, wt);
  qkv_gemm<<<dim3(32, 8, 3), dim3(512), 0, stream>>>(xb, wt, bq, bk, bv, qo, ko, vo);
  sgemm<<<dim3(136, BATCH), dim3(256), 0, stream>>>(qo, ko, S);
  softmax_rows<<<dim3(BATCH * SEQ), dim3(256), 0, stream>>>(S, P);
  pvgemm<<<dim3(8, BATCH, 16), dim3(256), 0, stream>>>(P, vo, out);
}